// Round 18
// baseline (281.976 us; speedup 1.0000x reference)
//
#include <hip/hip_runtime.h>

#define FEATS 64
#define BTILE 32         // dst nodes per build bucket
#define MAX_NB 3200      // supports N <= 102400 at BTILE=32
#define CH 8192          // edges per build chunk (196 chunks)
#define SORT_CAP 2048    // max bucket size sorter handles (avg 512)
#define NPW 4            // nodes per wave in agg_proj (16 lanes per node, fp32 row)

// ---- scale: hs = feat * norm (fp32, float4-vectorized) ----
__global__ __launch_bounds__(256) void scale_kernel(
    const float* __restrict__ feat, const float* __restrict__ norm,
    float* __restrict__ out, int n4) {
    const int i = blockIdx.x * 256 + threadIdx.x;
    if (i >= n4) return;
    float4 v = reinterpret_cast<const float4*>(feat)[i];
    const float nv = norm[i >> 4];                 // 16 float4 per 64-feat row
    v.x *= nv; v.y *= nv; v.z *= nv; v.w *= nv;
    reinterpret_cast<float4*>(out)[i] = v;
}

// ---- build pass 1: per-chunk histogram over dst buckets ----
__global__ __launch_bounds__(1024) void hist_pass(
    const int* __restrict__ dst, int* __restrict__ hist, int E, int NB) {
    __shared__ int lh[MAX_NB];
    for (int i = threadIdx.x; i < NB; i += 1024) lh[i] = 0;
    __syncthreads();
    const int k  = blockIdx.x;
    const int e0 = k * CH, e1 = min(E, e0 + CH);
    for (int e = e0 + threadIdx.x; e < e1; e += 1024)
        atomicAdd(&lh[dst[e] >> 5], 1);
    __syncthreads();
    for (int b = threadIdx.x; b < NB; b += 1024)
        hist[(size_t)k * NB + b] = lh[b];
}

// ---- build pass 2: per-bucket exclusive scan across chunks (in place), totals ----
__global__ __launch_bounds__(256) void bucket_scan(
    int* hist, int* __restrict__ btotal, int NB, int NCHUNK) {
    __shared__ int sa[256], sb[256];
    const int b = blockIdx.x, t = threadIdx.x;
    const int v = (t < NCHUNK) ? hist[(size_t)t * NB + b] : 0;
    sa[t] = v;
    __syncthreads();
    int *cur = sa, *nxt = sb;
    for (int off = 1; off < 256; off <<= 1) {
        nxt[t] = cur[t] + ((t >= off) ? cur[t - off] : 0);
        __syncthreads();
        int* tmp = cur; cur = nxt; nxt = tmp;
    }
    if (t < NCHUNK) hist[(size_t)t * NB + b] = cur[t] - v;   // exclusive
    if (t == 255) btotal[b] = cur[255];
}

// ---- build pass 3: single-block chunked exclusive scan of bucket totals ----
__global__ __launch_bounds__(1024) void base_scan(
    const int* __restrict__ btotal, int* __restrict__ bstart, int NB, int E) {
    __shared__ int sa[1024], sb[1024];
    __shared__ int carry;
    const int t = threadIdx.x;
    if (t == 0) carry = 0;
    __syncthreads();
    for (int base = 0; base < NB; base += 1024) {
        const int i = base + t;
        const int v = (i < NB) ? btotal[i] : 0;
        sa[t] = v;
        __syncthreads();
        int *cur = sa, *nxt = sb;
        for (int off = 1; off < 1024; off <<= 1) {
            nxt[t] = cur[t] + ((t >= off) ? cur[t - off] : 0);
            __syncthreads();
            int* tmp = cur; cur = nxt; nxt = tmp;
        }
        const int c = carry;
        if (i < NB) bstart[i] = c + cur[t] - v;
        __syncthreads();
        if (t == 1023) carry = c + cur[1023];
        __syncthreads();
    }
    if (t == 0) bstart[NB] = E;
}

// ---- build pass 4: scatter packed (dstlow<<26 | src) via per-block LDS cursors ----
__global__ __launch_bounds__(1024) void scatter_pack(
    const int* __restrict__ src, const int* __restrict__ dst,
    const int* __restrict__ prebase, const int* __restrict__ bstart,
    unsigned int* __restrict__ packed, int E, int NB) {
    __shared__ int cur[MAX_NB];
    const int k = blockIdx.x;
    for (int b = threadIdx.x; b < NB; b += 1024)
        cur[b] = bstart[b] + prebase[(size_t)k * NB + b];
    __syncthreads();
    const int e0 = k * CH, e1 = min(E, e0 + CH);
    for (int e = e0 + threadIdx.x; e < e1; e += 1024) {
        const int d = dst[e];
        const int p = atomicAdd(&cur[d >> 5], 1);
        packed[p] = ((unsigned)(d & 31) << 26) | (unsigned)src[e];
    }
}

// ---- build pass 5: in-place counting sort of each bucket by dst-low + node rowptr ----
__global__ __launch_bounds__(256) void sort_bucket(
    unsigned int* packed, const int* __restrict__ bstart,
    int* __restrict__ rowptr, int NB, int E) {
    __shared__ unsigned ent[SORT_CAP];
    __shared__ int cnt[BTILE];
    __shared__ int base[BTILE];
    const int b = blockIdx.x;
    const int beg = bstart[b], end = bstart[b + 1];
    const int n = end - beg;
    const int t = threadIdx.x;
    if (t < BTILE) cnt[t] = 0;
    __syncthreads();
    if (n <= SORT_CAP) {
        for (int i = t; i < n; i += 256) {
            const unsigned v = packed[beg + i];
            ent[i] = v;
            atomicAdd(&cnt[v >> 26], 1);
        }
    } else {
        for (int i = t; i < n; i += 256) atomicAdd(&cnt[packed[beg + i] >> 26], 1);
    }
    __syncthreads();
    if (t == 0) {
        int run = 0;
        for (int i = 0; i < BTILE; ++i) {
            const int c = cnt[i]; base[i] = run; cnt[i] = run; run += c;
        }
    }
    __syncthreads();
    if (t < BTILE) rowptr[b * BTILE + t] = beg + base[t];
    if (b == NB - 1 && t == 0) rowptr[NB * BTILE] = E;
    if (n <= SORT_CAP) {
        for (int i = t; i < n; i += 256) {
            const unsigned v = ent[i];
            const int p = atomicAdd(&cnt[v >> 26], 1);
            packed[beg + p] = v;
        }
    }
}

__device__ __forceinline__ float4 rowf(const float* hs, unsigned pk, int chunk) {
    return *((const float4*)((const char*)hs + (size_t)(pk & 0x3FFFFFFu) * 256) + chunk);
}

// ---- fused aggregate + project: ONE WAVE per block, 4 nodes, SLOT = NODE, fp32 ----
// lane(slot=lane>>4, chunk=lane&15): 16 lanes cover one full fp32 row (256 B) per
// load; 4 adds/iter, ZERO bf16 unpack (r17's 16 VALU/iter gather). No cross-lane
// reduce, no bpermute. Epilogue = proven rolled k-outer (r14/r15 spill lesson).
__global__ __launch_bounds__(64, 4) void agg_proj(
    const unsigned int* __restrict__ packed, const int* __restrict__ rowptr,
    const float* __restrict__ hs, const float* __restrict__ norm,
    const float* __restrict__ W, const float* __restrict__ bias,
    float* __restrict__ out, int N, int E, int mode) {
    __shared__ float accs[NPW * FEATS];          // 1 KB, wave-private
    const int lane  = threadIdx.x & 63;
    const int slot  = lane >> 4;                 // 0..3 -> node
    const int chunk = lane & 15;                 // float4 index within row
    const int node0 = blockIdx.x * NPW;
    const int node  = node0 + slot;

    float4 a = make_float4(0.f, 0.f, 0.f, 0.f);

    int rb = 0, deg = 0;
    if (node < N) { rb = rowptr[node]; deg = rowptr[node + 1] - rb; }

    if (deg > 0) {
        // 2-ahead word / 1-ahead row software pipeline (all per-lane registers)
        unsigned pk0 = packed[rb];
        unsigned pk1 = packed[rb + min(1, deg - 1)];
        float4 d0 = rowf(hs, pk0, chunk);
        for (int j = 1; j < deg; ++j) {
            const unsigned pk2 = packed[rb + min(j + 1, deg - 1)];
            const float4 d1 = rowf(hs, pk1, chunk);
            a.x += d0.x; a.y += d0.y; a.z += d0.z; a.w += d0.w;
            d0 = d1; pk1 = pk2;
        }
        a.x += d0.x; a.y += d0.y; a.z += d0.z; a.w += d0.w;
    }

    // write-once row: one ds_write_b128 per lane, no RMW, no reduce
    *(float4*)&accs[slot * FEATS + chunk * 4] = a;
    __syncthreads();                             // single wave: trivial

    // epilogue: k-outer GEMV, ROLLED outer loop (16 iters) -- proven form.
    float s[NPW];
#pragma unroll
    for (int i = 0; i < NPW; ++i) s[i] = 0.f;
#pragma unroll 1
    for (int k4 = 0; k4 < 16; ++k4) {
        const float w0 = W[(4 * k4 + 0) * FEATS + lane];
        const float w1 = W[(4 * k4 + 1) * FEATS + lane];
        const float w2 = W[(4 * k4 + 2) * FEATS + lane];
        const float w3 = W[(4 * k4 + 3) * FEATS + lane];
#pragma unroll
        for (int i = 0; i < NPW; ++i) {
            const float4 v = *(const float4*)&accs[i * FEATS + 4 * k4];  // uniform b128
            s[i] = fmaf(v.w, w3, fmaf(v.z, w2, fmaf(v.y, w1, fmaf(v.x, w0, s[i]))));
        }
    }
    const float bi = bias[lane];
#pragma unroll
    for (int i = 0; i < NPW; ++i) {
        const int onode = node0 + i;
        if (onode >= N) break;
        const float nv = norm[onode];
        float o = fmaf(s[i], nv, bi);
        if (mode) o = fmaxf(o, 0.f) * nv;        // relu + next layer's pre-scale
        out[(size_t)onode * FEATS + lane] = o;
    }
}

extern "C" void kernel_launch(void* const* d_in, const int* in_sizes, int n_in,
                              void* d_out, int out_size, void* d_ws, size_t ws_size,
                              hipStream_t stream) {
    const float* feat = (const float*)d_in[0];
    const float* norm = (const float*)d_in[1];
    const int*   src  = (const int*)d_in[2];
    const int*   dst  = (const int*)d_in[3];
    const float* W0   = (const float*)d_in[4];
    const float* b0   = (const float*)d_in[5];
    const float* W1   = (const float*)d_in[6];
    const float* b1   = (const float*)d_in[7];
    const float* W2   = (const float*)d_in[8];
    const float* b2   = (const float*)d_in[9];

    float* out = (float*)d_out;
    const int N = in_sizes[0] / FEATS;
    const int E = in_sizes[2];
    const int NB = (N + BTILE - 1) / BTILE;        // 3125
    const int NCHUNK = (E + CH - 1) / CH;          // 196

    // workspace layout (~35 MB): fp32 H0 ping-pongs with d_out itself (r2 pattern)
    float*    H0     = (float*)d_ws;                        // [N*64] fp32
    unsigned* packed = (unsigned*)(H0 + (size_t)N * FEATS); // [E]
    int*      hist   = (int*)(packed + E);                  // [NCHUNK*NB]
    int*      btotal = hist + (size_t)NCHUNK * NB;          // [NB]
    int*      bstart = btotal + NB;                         // [NB+1]
    int*      rowptr = bstart + NB + 1;                     // [NB*BTILE+1]

    // ---- build node-sorted edge list + node rowptr (once, reused by 3 layers) ----
    hist_pass<<<NCHUNK, 1024, 0, stream>>>(dst, hist, E, NB);
    bucket_scan<<<NB, 256, 0, stream>>>(hist, btotal, NB, NCHUNK);
    base_scan<<<1, 1024, 0, stream>>>(btotal, bstart, NB, E);
    scatter_pack<<<NCHUNK, 1024, 0, stream>>>(src, dst, hist, bstart, packed, E, NB);
    sort_bucket<<<NB, 256, 0, stream>>>(packed, bstart, rowptr, NB, E);

    const int agrid = (N + NPW - 1) / NPW;         // 25000 one-wave blocks
    const int sgrid = (N * 16 + 255) / 256;

    // hs0 = feat*norm (fp32)
    scale_kernel<<<sgrid, 256, 0, stream>>>(feat, norm, H0, N * 16);

    // layer 0: H0 -> out   (fp32 hs1 = relu((agg H0)@W0*n + b0)*n)
    agg_proj<<<agrid, 64, 0, stream>>>(packed, rowptr, H0, norm, W0, b0, out, N, E, 1);
    // layer 1: out -> H0   (fp32 hs2)
    agg_proj<<<agrid, 64, 0, stream>>>(packed, rowptr, out, norm, W1, b1, H0, N, E, 1);
    // layer 2: H0 -> out   (final, no relu/prescale)
    agg_proj<<<agrid, 64, 0, stream>>>(packed, rowptr, H0, norm, W2, b2, out, N, E, 0);
}

// Round 19
// 196.355 us; speedup vs baseline: 1.4361x; 1.4361x over previous
//
#include <hip/hip_runtime.h>

#define FEATS 64
#define BTILE 32         // dst nodes per build bucket
#define MAX_NB 3200      // supports N <= 102400 at BTILE=32
#define CH 8192          // edges per build chunk (196 chunks)
#define SORT_CAP 2048    // max bucket size sorter handles (avg 512)
#define NPW 8            // nodes per wave in agg_proj

__device__ __forceinline__ float bf2f(unsigned short b) {
    unsigned u = (unsigned)b << 16;
    float f; __builtin_memcpy(&f, &u, 4); return f;
}
__device__ __forceinline__ unsigned short f2bf(float f) {   // round-to-nearest-even
    unsigned u; __builtin_memcpy(&u, &f, 4);
    u += 0x7FFFu + ((u >> 16) & 1u);
    return (unsigned short)(u >> 16);
}
__device__ __forceinline__ float lo16(unsigned u) {
    unsigned v = u << 16; float f; __builtin_memcpy(&f, &v, 4); return f;
}
__device__ __forceinline__ float hi16(unsigned u) {
    unsigned v = u & 0xFFFF0000u; float f; __builtin_memcpy(&f, &v, 4); return f;
}

// ---- scale: hs = bf16(feat * norm); 4 elems/thread ----
__global__ __launch_bounds__(256) void scale_kernel(
    const float* __restrict__ feat, const float* __restrict__ norm,
    unsigned short* __restrict__ out, int n4) {
    const int i = blockIdx.x * 256 + threadIdx.x;
    if (i >= n4) return;
    float4 v = reinterpret_cast<const float4*>(feat)[i];
    const float nv = norm[i >> 4];
    uint2 p;
    p.x = (unsigned)f2bf(v.x * nv) | ((unsigned)f2bf(v.y * nv) << 16);
    p.y = (unsigned)f2bf(v.z * nv) | ((unsigned)f2bf(v.w * nv) << 16);
    reinterpret_cast<uint2*>(out)[i] = p;
}

// ---- build pass 1: per-chunk histogram over dst buckets ----
__global__ __launch_bounds__(1024) void hist_pass(
    const int* __restrict__ dst, int* __restrict__ hist, int E, int NB) {
    __shared__ int lh[MAX_NB];
    for (int i = threadIdx.x; i < NB; i += 1024) lh[i] = 0;
    __syncthreads();
    const int k  = blockIdx.x;
    const int e0 = k * CH, e1 = min(E, e0 + CH);
    for (int e = e0 + threadIdx.x; e < e1; e += 1024)
        atomicAdd(&lh[dst[e] >> 5], 1);
    __syncthreads();
    for (int b = threadIdx.x; b < NB; b += 1024)
        hist[(size_t)k * NB + b] = lh[b];
}

// ---- build pass 2: per-bucket exclusive scan across chunks (in place), totals ----
__global__ __launch_bounds__(256) void bucket_scan(
    int* hist, int* __restrict__ btotal, int NB, int NCHUNK) {
    __shared__ int sa[256], sb[256];
    const int b = blockIdx.x, t = threadIdx.x;
    const int v = (t < NCHUNK) ? hist[(size_t)t * NB + b] : 0;
    sa[t] = v;
    __syncthreads();
    int *cur = sa, *nxt = sb;
    for (int off = 1; off < 256; off <<= 1) {
        nxt[t] = cur[t] + ((t >= off) ? cur[t - off] : 0);
        __syncthreads();
        int* tmp = cur; cur = nxt; nxt = tmp;
    }
    if (t < NCHUNK) hist[(size_t)t * NB + b] = cur[t] - v;   // exclusive
    if (t == 255) btotal[b] = cur[255];
}

// ---- build pass 3: single-block chunked exclusive scan of bucket totals ----
__global__ __launch_bounds__(1024) void base_scan(
    const int* __restrict__ btotal, int* __restrict__ bstart, int NB, int E) {
    __shared__ int sa[1024], sb[1024];
    __shared__ int carry;
    const int t = threadIdx.x;
    if (t == 0) carry = 0;
    __syncthreads();
    for (int base = 0; base < NB; base += 1024) {
        const int i = base + t;
        const int v = (i < NB) ? btotal[i] : 0;
        sa[t] = v;
        __syncthreads();
        int *cur = sa, *nxt = sb;
        for (int off = 1; off < 1024; off <<= 1) {
            nxt[t] = cur[t] + ((t >= off) ? cur[t - off] : 0);
            __syncthreads();
            int* tmp = cur; cur = nxt; nxt = tmp;
        }
        const int c = carry;
        if (i < NB) bstart[i] = c + cur[t] - v;
        __syncthreads();
        if (t == 1023) carry = c + cur[1023];
        __syncthreads();
    }
    if (t == 0) bstart[NB] = E;
}

// ---- build pass 4: scatter packed (dstlow<<26 | src) via per-block LDS cursors ----
__global__ __launch_bounds__(1024) void scatter_pack(
    const int* __restrict__ src, const int* __restrict__ dst,
    const int* __restrict__ prebase, const int* __restrict__ bstart,
    unsigned int* __restrict__ packed, int E, int NB) {
    __shared__ int cur[MAX_NB];
    const int k = blockIdx.x;
    for (int b = threadIdx.x; b < NB; b += 1024)
        cur[b] = bstart[b] + prebase[(size_t)k * NB + b];
    __syncthreads();
    const int e0 = k * CH, e1 = min(E, e0 + CH);
    for (int e = e0 + threadIdx.x; e < e1; e += 1024) {
        const int d = dst[e];
        const int p = atomicAdd(&cur[d >> 5], 1);
        packed[p] = ((unsigned)(d & 31) << 26) | (unsigned)src[e];
    }
}

// ---- build pass 5: in-place counting sort of each bucket by dst-low + node rowptr ----
__global__ __launch_bounds__(256) void sort_bucket(
    unsigned int* packed, const int* __restrict__ bstart,
    int* __restrict__ rowptr, int NB, int E) {
    __shared__ unsigned ent[SORT_CAP];
    __shared__ int cnt[BTILE];
    __shared__ int base[BTILE];
    const int b = blockIdx.x;
    const int beg = bstart[b], end = bstart[b + 1];
    const int n = end - beg;
    const int t = threadIdx.x;
    if (t < BTILE) cnt[t] = 0;
    __syncthreads();
    if (n <= SORT_CAP) {
        for (int i = t; i < n; i += 256) {
            const unsigned v = packed[beg + i];
            ent[i] = v;
            atomicAdd(&cnt[v >> 26], 1);
        }
    } else {
        for (int i = t; i < n; i += 256) atomicAdd(&cnt[packed[beg + i] >> 26], 1);
    }
    __syncthreads();
    if (t == 0) {
        int run = 0;
        for (int i = 0; i < BTILE; ++i) {
            const int c = cnt[i]; base[i] = run; cnt[i] = run; run += c;
        }
    }
    __syncthreads();
    if (t < BTILE) rowptr[b * BTILE + t] = beg + base[t];
    if (b == NB - 1 && t == 0) rowptr[NB * BTILE] = E;
    if (n <= SORT_CAP) {
        for (int i = t; i < n; i += 256) {
            const unsigned v = ent[i];
            const int p = atomicAdd(&cnt[v >> 26], 1);
            packed[beg + p] = v;
        }
    }
}

#define ADD8(d) do { \
    a0 += lo16((d).x); a1 += hi16((d).x); \
    a2 += lo16((d).y); a3 += hi16((d).y); \
    a4 += lo16((d).z); a5 += hi16((d).z); \
    a6 += lo16((d).w); a7 += hi16((d).w); } while (0)

__device__ __forceinline__ uint4 row16(const unsigned short* hs, unsigned pk, int chunk) {
    return *((const uint4*)((const char*)hs + (size_t)(pk & 0x3FFFFFFu) * 128) + chunk);
}

// ---- fused aggregate + project: FOUR waves per block, SLOT = NODE, bf16 ----
// Each wave = r17's proven kernel verbatim (28 VGPR): own 8 nodes, own accs
// stripe, no inter-wave communication, NO barrier (r5-r8 precedent). 256-thr
// blocks lift the ~16 blocks/CU cap that held r17 at 58% occupancy.
// (256,4): cap 128 >= need ~30 -> no spill risk (r10-15 pendulum needs need>cap).
__global__ __launch_bounds__(256, 4) void agg_proj(
    const unsigned int* __restrict__ packed, const int* __restrict__ rowptr,
    const unsigned short* __restrict__ hs, const float* __restrict__ norm,
    const float* __restrict__ W, const float* __restrict__ bias,
    void* __restrict__ outv, int N, int E, int mode) {
    __shared__ float accs[4][NPW * FEATS];       // 4 x 2 KB, wave-private stripes
    const int lane  = threadIdx.x & 63;
    const int w     = threadIdx.x >> 6;
    const int slot  = lane >> 3;
    const int chunk = lane & 7;
    const int node0 = (blockIdx.x * 4 + w) * NPW;
    const int node  = node0 + slot;              // this lane's node
    float* As = accs[w];

    float a0 = 0.f, a1 = 0.f, a2 = 0.f, a3 = 0.f,
          a4 = 0.f, a5 = 0.f, a6 = 0.f, a7 = 0.f;

    int rb = 0, deg = 0;
    if (node < N) { rb = rowptr[node]; deg = rowptr[node + 1] - rb; }

    if (deg > 0) {
        // 2-ahead word / 1-ahead row software pipeline (all per-lane registers)
        unsigned pk0 = packed[rb];
        unsigned pk1 = packed[rb + min(1, deg - 1)];
        uint4 d0 = row16(hs, pk0, chunk);
        for (int j = 1; j < deg; ++j) {
            const unsigned pk2 = packed[rb + min(j + 1, deg - 1)];
            const uint4 d1 = row16(hs, pk1, chunk);   // pk1 loaded last iter
            ADD8(d0);                                  // consume row loaded last iter
            d0 = d1; pk1 = pk2;
        }
        ADD8(d0);
    }

    // write-once row: no RMW, no reduce; wave-private stripe, compiler orders
    // the LDS RAW via lgkmcnt (no block barrier needed -- r5-r8 precedent)
    {
        float4* dstp = (float4*)&As[slot * FEATS + chunk * 8];
        dstp[0] = make_float4(a0, a1, a2, a3);
        dstp[1] = make_float4(a4, a5, a6, a7);
    }

    // epilogue: k-outer GEMV, ROLLED outer loop (16 iters) -- proven form
    // (r14/r15: unrolling this loop triggers load-hoisting -> spill).
    float s[NPW];
#pragma unroll
    for (int i = 0; i < NPW; ++i) s[i] = 0.f;
#pragma unroll 1
    for (int k4 = 0; k4 < 16; ++k4) {
        const float w0 = W[(4 * k4 + 0) * FEATS + lane];
        const float w1 = W[(4 * k4 + 1) * FEATS + lane];
        const float w2 = W[(4 * k4 + 2) * FEATS + lane];
        const float w3 = W[(4 * k4 + 3) * FEATS + lane];
#pragma unroll
        for (int i = 0; i < NPW; ++i) {
            const float4 a = *(const float4*)&As[i * FEATS + 4 * k4];  // uniform b128
            s[i] = fmaf(a.w, w3, fmaf(a.z, w2, fmaf(a.y, w1, fmaf(a.x, w0, s[i]))));
        }
    }
    const float bi = bias[lane];
#pragma unroll
    for (int i = 0; i < NPW; ++i) {
        const int onode = node0 + i;
        if (onode >= N) break;
        const float nv = norm[onode];
        float o = fmaf(s[i], nv, bi);
        if (mode) {                                // relu + next prescale -> bf16
            o = fmaxf(o, 0.f) * nv;
            ((unsigned short*)outv)[(size_t)onode * FEATS + lane] = f2bf(o);
        } else {                                   // final fp32
            ((float*)outv)[(size_t)onode * FEATS + lane] = o;
        }
    }
}

extern "C" void kernel_launch(void* const* d_in, const int* in_sizes, int n_in,
                              void* d_out, int out_size, void* d_ws, size_t ws_size,
                              hipStream_t stream) {
    const float* feat = (const float*)d_in[0];
    const float* norm = (const float*)d_in[1];
    const int*   src  = (const int*)d_in[2];
    const int*   dst  = (const int*)d_in[3];
    const float* W0   = (const float*)d_in[4];
    const float* b0   = (const float*)d_in[5];
    const float* W1   = (const float*)d_in[6];
    const float* b1   = (const float*)d_in[7];
    const float* W2   = (const float*)d_in[8];
    const float* b2   = (const float*)d_in[9];

    float* out = (float*)d_out;
    const int N = in_sizes[0] / FEATS;
    const int E = in_sizes[2];
    const int NB = (N + BTILE - 1) / BTILE;        // 3125
    const int NCHUNK = (E + CH - 1) / CH;          // 196

    // workspace layout (~35 MB)
    unsigned short* H0 = (unsigned short*)d_ws;             // [N*64] bf16 ping
    unsigned short* H1 = H0 + (size_t)N * FEATS;            // [N*64] bf16 pong
    unsigned* packed = (unsigned*)(H1 + (size_t)N * FEATS); // [E]
    int*      hist   = (int*)(packed + E);                  // [NCHUNK*NB]
    int*      btotal = hist + (size_t)NCHUNK * NB;          // [NB]
    int*      bstart = btotal + NB;                         // [NB+1]
    int*      rowptr = bstart + NB + 1;                     // [NB*BTILE+1]

    // ---- build node-sorted edge list + node rowptr (once, reused by 3 layers) ----
    hist_pass<<<NCHUNK, 1024, 0, stream>>>(dst, hist, E, NB);
    bucket_scan<<<NB, 256, 0, stream>>>(hist, btotal, NB, NCHUNK);
    base_scan<<<1, 1024, 0, stream>>>(btotal, bstart, NB, E);
    scatter_pack<<<NCHUNK, 1024, 0, stream>>>(src, dst, hist, bstart, packed, E, NB);
    sort_bucket<<<NB, 256, 0, stream>>>(packed, bstart, rowptr, NB, E);

    const int agrid = (N + 4 * NPW - 1) / (4 * NPW);   // 3125 4-wave blocks
    const int sgrid = (N * 16 + 255) / 256;

    // hs0 = bf16(feat*norm)
    scale_kernel<<<sgrid, 256, 0, stream>>>(feat, norm, H0, N * 16);

    // layer 0: H0 -> H1 (bf16 hs1)
    agg_proj<<<agrid, 256, 0, stream>>>(packed, rowptr, H0, norm, W0, b0, H1, N, E, 1);
    // layer 1: H1 -> H0 (bf16 hs2)
    agg_proj<<<agrid, 256, 0, stream>>>(packed, rowptr, H1, norm, W1, b1, H0, N, E, 1);
    // layer 2: H0 -> out (fp32 final)
    agg_proj<<<agrid, 256, 0, stream>>>(packed, rowptr, H0, norm, W2, b2, out, N, E, 0);
}

// Round 20
// 190.022 us; speedup vs baseline: 1.4839x; 1.0333x over previous
//
#include <hip/hip_runtime.h>

#define FEATS 64
#define BTILE 32         // dst nodes per build bucket
#define MAX_NB 3200      // supports N <= 102400 at BTILE=32
#define CH 8192          // edges per build chunk (196 chunks)
#define SORT_CAP 2048    // max bucket size sorter handles (avg 512)
#define NPW 8            // nodes per wave in agg_proj

__device__ __forceinline__ float bf2f(unsigned short b) {
    unsigned u = (unsigned)b << 16;
    float f; __builtin_memcpy(&f, &u, 4); return f;
}
__device__ __forceinline__ unsigned short f2bf(float f) {   // round-to-nearest-even
    unsigned u; __builtin_memcpy(&u, &f, 4);
    u += 0x7FFFu + ((u >> 16) & 1u);
    return (unsigned short)(u >> 16);
}
__device__ __forceinline__ float lo16(unsigned u) {
    unsigned v = u << 16; float f; __builtin_memcpy(&f, &v, 4); return f;
}
__device__ __forceinline__ float hi16(unsigned u) {
    unsigned v = u & 0xFFFF0000u; float f; __builtin_memcpy(&f, &v, 4); return f;
}

// ---- scale: hs = bf16(feat * norm); 4 elems/thread ----
__global__ __launch_bounds__(256) void scale_kernel(
    const float* __restrict__ feat, const float* __restrict__ norm,
    unsigned short* __restrict__ out, int n4) {
    const int i = blockIdx.x * 256 + threadIdx.x;
    if (i >= n4) return;
    float4 v = reinterpret_cast<const float4*>(feat)[i];
    const float nv = norm[i >> 4];
    uint2 p;
    p.x = (unsigned)f2bf(v.x * nv) | ((unsigned)f2bf(v.y * nv) << 16);
    p.y = (unsigned)f2bf(v.z * nv) | ((unsigned)f2bf(v.w * nv) << 16);
    reinterpret_cast<uint2*>(out)[i] = p;
}

// ---- build pass 1: per-chunk histogram over dst buckets ----
__global__ __launch_bounds__(1024) void hist_pass(
    const int* __restrict__ dst, int* __restrict__ hist, int E, int NB) {
    __shared__ int lh[MAX_NB];
    for (int i = threadIdx.x; i < NB; i += 1024) lh[i] = 0;
    __syncthreads();
    const int k  = blockIdx.x;
    const int e0 = k * CH, e1 = min(E, e0 + CH);
    for (int e = e0 + threadIdx.x; e < e1; e += 1024)
        atomicAdd(&lh[dst[e] >> 5], 1);
    __syncthreads();
    for (int b = threadIdx.x; b < NB; b += 1024)
        hist[(size_t)k * NB + b] = lh[b];
}

// ---- build pass 2: per-bucket exclusive scan across chunks (in place), totals ----
__global__ __launch_bounds__(256) void bucket_scan(
    int* hist, int* __restrict__ btotal, int NB, int NCHUNK) {
    __shared__ int sa[256], sb[256];
    const int b = blockIdx.x, t = threadIdx.x;
    const int v = (t < NCHUNK) ? hist[(size_t)t * NB + b] : 0;
    sa[t] = v;
    __syncthreads();
    int *cur = sa, *nxt = sb;
    for (int off = 1; off < 256; off <<= 1) {
        nxt[t] = cur[t] + ((t >= off) ? cur[t - off] : 0);
        __syncthreads();
        int* tmp = cur; cur = nxt; nxt = tmp;
    }
    if (t < NCHUNK) hist[(size_t)t * NB + b] = cur[t] - v;   // exclusive
    if (t == 255) btotal[b] = cur[255];
}

// ---- build pass 3: single-block chunked exclusive scan of bucket totals ----
__global__ __launch_bounds__(1024) void base_scan(
    const int* __restrict__ btotal, int* __restrict__ bstart, int NB, int E) {
    __shared__ int sa[1024], sb[1024];
    __shared__ int carry;
    const int t = threadIdx.x;
    if (t == 0) carry = 0;
    __syncthreads();
    for (int base = 0; base < NB; base += 1024) {
        const int i = base + t;
        const int v = (i < NB) ? btotal[i] : 0;
        sa[t] = v;
        __syncthreads();
        int *cur = sa, *nxt = sb;
        for (int off = 1; off < 1024; off <<= 1) {
            nxt[t] = cur[t] + ((t >= off) ? cur[t - off] : 0);
            __syncthreads();
            int* tmp = cur; cur = nxt; nxt = tmp;
        }
        const int c = carry;
        if (i < NB) bstart[i] = c + cur[t] - v;
        __syncthreads();
        if (t == 1023) carry = c + cur[1023];
        __syncthreads();
    }
    if (t == 0) bstart[NB] = E;
}

// ---- build pass 4: scatter packed (dstlow<<26 | src) via per-block LDS cursors ----
__global__ __launch_bounds__(1024) void scatter_pack(
    const int* __restrict__ src, const int* __restrict__ dst,
    const int* __restrict__ prebase, const int* __restrict__ bstart,
    unsigned int* __restrict__ packed, int E, int NB) {
    __shared__ int cur[MAX_NB];
    const int k = blockIdx.x;
    for (int b = threadIdx.x; b < NB; b += 1024)
        cur[b] = bstart[b] + prebase[(size_t)k * NB + b];
    __syncthreads();
    const int e0 = k * CH, e1 = min(E, e0 + CH);
    for (int e = e0 + threadIdx.x; e < e1; e += 1024) {
        const int d = dst[e];
        const int p = atomicAdd(&cur[d >> 5], 1);
        packed[p] = ((unsigned)(d & 31) << 26) | (unsigned)src[e];
    }
}

// ---- build pass 5: in-place counting sort of each bucket by dst-low + node rowptr ----
__global__ __launch_bounds__(256) void sort_bucket(
    unsigned int* packed, const int* __restrict__ bstart,
    int* __restrict__ rowptr, int NB, int E) {
    __shared__ unsigned ent[SORT_CAP];
    __shared__ int cnt[BTILE];
    __shared__ int base[BTILE];
    const int b = blockIdx.x;
    const int beg = bstart[b], end = bstart[b + 1];
    const int n = end - beg;
    const int t = threadIdx.x;
    if (t < BTILE) cnt[t] = 0;
    __syncthreads();
    if (n <= SORT_CAP) {
        for (int i = t; i < n; i += 256) {
            const unsigned v = packed[beg + i];
            ent[i] = v;
            atomicAdd(&cnt[v >> 26], 1);
        }
    } else {
        for (int i = t; i < n; i += 256) atomicAdd(&cnt[packed[beg + i] >> 26], 1);
    }
    __syncthreads();
    if (t == 0) {
        int run = 0;
        for (int i = 0; i < BTILE; ++i) {
            const int c = cnt[i]; base[i] = run; cnt[i] = run; run += c;
        }
    }
    __syncthreads();
    if (t < BTILE) rowptr[b * BTILE + t] = beg + base[t];
    if (b == NB - 1 && t == 0) rowptr[NB * BTILE] = E;
    if (n <= SORT_CAP) {
        for (int i = t; i < n; i += 256) {
            const unsigned v = ent[i];
            const int p = atomicAdd(&cnt[v >> 26], 1);
            packed[beg + p] = v;
        }
    }
}

#define ADD8(d) do { \
    a0 += lo16((d).x); a1 += hi16((d).x); \
    a2 += lo16((d).y); a3 += hi16((d).y); \
    a4 += lo16((d).z); a5 += hi16((d).z); \
    a6 += lo16((d).w); a7 += hi16((d).w); } while (0)

__device__ __forceinline__ uint4 row16(const unsigned short* hs, unsigned pk, int chunk) {
    return *((const uint4*)((const char*)hs + (size_t)(pk & 0x3FFFFFFu) * 128) + chunk);
}

// ---- fused aggregate + project: ONE WAVE per block, SLOT = NODE gather ----
// r17 proven form: 28 VGPR, zero spill, agg 46 us. lane(slot,chunk) accumulates
// node node0+slot's elements [8c..8c+7] in registers; no cross-lane reduce, no
// bpermute; degree divergence via exec mask. Rolled k-outer epilogue (r14/r15
// spill lesson). Byte-bound on the L2/L3 random-gather path (~4.4 TB/s service).
__global__ __launch_bounds__(64, 4) void agg_proj(
    const unsigned int* __restrict__ packed, const int* __restrict__ rowptr,
    const unsigned short* __restrict__ hs, const float* __restrict__ norm,
    const float* __restrict__ W, const float* __restrict__ bias,
    void* __restrict__ outv, int N, int E, int mode) {
    __shared__ float accs[NPW * FEATS];          // 2 KB, wave-private
    const int lane  = threadIdx.x & 63;
    const int slot  = lane >> 3;
    const int chunk = lane & 7;
    const int node0 = blockIdx.x * NPW;
    const int node  = node0 + slot;              // this lane's node

    float a0 = 0.f, a1 = 0.f, a2 = 0.f, a3 = 0.f,
          a4 = 0.f, a5 = 0.f, a6 = 0.f, a7 = 0.f;

    int rb = 0, deg = 0;
    if (node < N) { rb = rowptr[node]; deg = rowptr[node + 1] - rb; }

    if (deg > 0) {
        // 2-ahead word / 1-ahead row software pipeline (all per-lane registers)
        unsigned pk0 = packed[rb];
        unsigned pk1 = packed[rb + min(1, deg - 1)];
        uint4 d0 = row16(hs, pk0, chunk);
        for (int j = 1; j < deg; ++j) {
            const unsigned pk2 = packed[rb + min(j + 1, deg - 1)];
            const uint4 d1 = row16(hs, pk1, chunk);   // pk1 loaded last iter
            ADD8(d0);                                  // consume row loaded last iter
            d0 = d1; pk1 = pk2;
        }
        ADD8(d0);
    }

    // write-once row: 2 x ds_write_b128 per wave total (no RMW, no reduce)
    {
        float4* dstp = (float4*)&accs[slot * FEATS + chunk * 8];
        dstp[0] = make_float4(a0, a1, a2, a3);
        dstp[1] = make_float4(a4, a5, a6, a7);
    }
    __syncthreads();                               // single wave: trivial

    // epilogue: k-outer GEMV, ROLLED outer loop (16 iters) -- proven form.
    float s[NPW];
#pragma unroll
    for (int i = 0; i < NPW; ++i) s[i] = 0.f;
#pragma unroll 1
    for (int k4 = 0; k4 < 16; ++k4) {
        const float w0 = W[(4 * k4 + 0) * FEATS + lane];
        const float w1 = W[(4 * k4 + 1) * FEATS + lane];
        const float w2 = W[(4 * k4 + 2) * FEATS + lane];
        const float w3 = W[(4 * k4 + 3) * FEATS + lane];
#pragma unroll
        for (int i = 0; i < NPW; ++i) {
            const float4 a = *(const float4*)&accs[i * FEATS + 4 * k4];  // uniform b128
            s[i] = fmaf(a.w, w3, fmaf(a.z, w2, fmaf(a.y, w1, fmaf(a.x, w0, s[i]))));
        }
    }
    const float bi = bias[lane];
#pragma unroll
    for (int i = 0; i < NPW; ++i) {
        const int onode = node0 + i;
        if (onode >= N) break;
        const float nv = norm[onode];
        float o = fmaf(s[i], nv, bi);
        if (mode) {                                // relu + next prescale -> bf16
            o = fmaxf(o, 0.f) * nv;
            ((unsigned short*)outv)[(size_t)onode * FEATS + lane] = f2bf(o);
        } else {                                   // final fp32
            ((float*)outv)[(size_t)onode * FEATS + lane] = o;
        }
    }
}

extern "C" void kernel_launch(void* const* d_in, const int* in_sizes, int n_in,
                              void* d_out, int out_size, void* d_ws, size_t ws_size,
                              hipStream_t stream) {
    const float* feat = (const float*)d_in[0];
    const float* norm = (const float*)d_in[1];
    const int*   src  = (const int*)d_in[2];
    const int*   dst  = (const int*)d_in[3];
    const float* W0   = (const float*)d_in[4];
    const float* b0   = (const float*)d_in[5];
    const float* W1   = (const float*)d_in[6];
    const float* b1   = (const float*)d_in[7];
    const float* W2   = (const float*)d_in[8];
    const float* b2   = (const float*)d_in[9];

    float* out = (float*)d_out;
    const int N = in_sizes[0] / FEATS;
    const int E = in_sizes[2];
    const int NB = (N + BTILE - 1) / BTILE;        // 3125
    const int NCHUNK = (E + CH - 1) / CH;          // 196

    // workspace layout (~35 MB)
    unsigned short* H0 = (unsigned short*)d_ws;             // [N*64] bf16 ping
    unsigned short* H1 = H0 + (size_t)N * FEATS;            // [N*64] bf16 pong
    unsigned* packed = (unsigned*)(H1 + (size_t)N * FEATS); // [E]
    int*      hist   = (int*)(packed + E);                  // [NCHUNK*NB]
    int*      btotal = hist + (size_t)NCHUNK * NB;          // [NB]
    int*      bstart = btotal + NB;                         // [NB+1]
    int*      rowptr = bstart + NB + 1;                     // [NB*BTILE+1]

    // ---- build node-sorted edge list + node rowptr (once, reused by 3 layers) ----
    hist_pass<<<NCHUNK, 1024, 0, stream>>>(dst, hist, E, NB);
    bucket_scan<<<NB, 256, 0, stream>>>(hist, btotal, NB, NCHUNK);
    base_scan<<<1, 1024, 0, stream>>>(btotal, bstart, NB, E);
    scatter_pack<<<NCHUNK, 1024, 0, stream>>>(src, dst, hist, bstart, packed, E, NB);
    sort_bucket<<<NB, 256, 0, stream>>>(packed, bstart, rowptr, NB, E);

    const int agrid = (N + NPW - 1) / NPW;         // 12500 one-wave blocks
    const int sgrid = (N * 16 + 255) / 256;

    // hs0 = bf16(feat*norm)
    scale_kernel<<<sgrid, 256, 0, stream>>>(feat, norm, H0, N * 16);

    // layer 0: H0 -> H1 (bf16 hs1)
    agg_proj<<<agrid, 64, 0, stream>>>(packed, rowptr, H0, norm, W0, b0, H1, N, E, 1);
    // layer 1: H1 -> H0 (bf16 hs2)
    agg_proj<<<agrid, 64, 0, stream>>>(packed, rowptr, H1, norm, W1, b1, H0, N, E, 1);
    // layer 2: H0 -> out (fp32 final)
    agg_proj<<<agrid, 64, 0, stream>>>(packed, rowptr, H0, norm, W2, b2, out, N, E, 0);
}